// Round 3
// baseline (33656.821 us; speedup 1.0000x reference)
//
#include <hip/hip_runtime.h>
#include <hip/hip_cooperative_groups.h>
#include <hip/hip_bf16.h>
#include <math.h>

namespace cg = cooperative_groups;

// Problem constants
#define B_ 256
#define S_ 128
#define F_ 128
#define H_ 512
#define A_ 512
#define C_ 128

#define DOT4(va, vb) ((va).x*(vb).x + (va).y*(vb).y + (va).z*(vb).z + (va).w*(vb).w)

// ---------------------------------------------------------------------------
// Activation staging: 64 rows x 32 k (fp32) tile, stored as float4 slots
// slot = kq*64 + (row ^ kq)  -> conflict-free write AND conflict-free
// per-lane b128 read (lane reads its row's k-quads).
// ---------------------------------------------------------------------------
__device__ __forceinline__ void stage_tile(float4* __restrict__ t,
                                           const float* __restrict__ base,
                                           size_t pitch, int kc, int tid)
{
#pragma unroll
    for (int u = 0; u < 2; ++u) {
        int idx = tid + u * 256;
        int bl = idx >> 3, kq = idx & 7;
        t[kq * 64 + (bl ^ kq)] =
            *(const float4*)(base + (size_t)bl * pitch + kc + kq * 4);
    }
}

__device__ __forceinline__ void read_inregs(const float4* __restrict__ t,
                                            int lane, float* __restrict__ in_r)
{
#pragma unroll
    for (int q = 0; q < 8; ++q) {
        float4 f = t[q * 64 + (lane ^ q)];
        in_r[4 * q + 0] = f.x; in_r[4 * q + 1] = f.y;
        in_r[4 * q + 2] = f.z; in_r[4 * q + 3] = f.w;
    }
}

// ---------------------------------------------------------------------------
// One GRU step phase. Block = 64 batch rows x 8 hidden cols.
// grid 256 blocks: bid>>6 -> batch quarter, bid&63 -> j-tile.
// Wave = 64 lanes <-> 64 batch rows; each wave owns 2 consecutive j's
// (wave-uniform -> weight reads become scalar loads).
// ---------------------------------------------------------------------------
__device__ __forceinline__ void gru_phase(
    int tid, int bid,
    const float* __restrict__ xin, size_t xpitch, int xK,
    const float* __restrict__ hin,
    const float* __restrict__ Wih, const float* __restrict__ Whh,
    const float* __restrict__ bih, const float* __restrict__ bhh,
    float* __restrict__ hout,
    float* __restrict__ encout, size_t enc_pitch,
    float4* __restrict__ tiles)
{
    const int lane = tid & 63;
    const int wvu  = __builtin_amdgcn_readfirstlane(tid >> 6);
    const int b0   = (bid >> 6) * 64;
    const int jA   = (bid & 63) * 8 + wvu * 2;
    const int b    = b0 + lane;

    float ar0 = 0.f, ar1 = 0.f, az0 = 0.f, az1 = 0.f;
    float ain0 = 0.f, ain1 = 0.f, ahn0 = 0.f, ahn1 = 0.f;
    float in_r[32];
    int par = 0;

    const float* xbase = xin + (size_t)b0 * xpitch;
    for (int kc = 0; kc < xK; kc += 32) {
        stage_tile(tiles + par * 512, xbase, xpitch, kc, tid);
        __syncthreads();
        read_inregs(tiles + par * 512, lane, in_r);
        par ^= 1;
        const float* Wr = Wih + (size_t)jA * xK + kc;
        const float* Wz = Wr + (size_t)H_ * xK;
        const float* Wn = Wz + (size_t)H_ * xK;
#pragma unroll
        for (int k = 0; k < 32; ++k) {
            float iv = in_r[k];
            ar0  = fmaf(iv, Wr[k], ar0);    ar1  = fmaf(iv, Wr[xK + k], ar1);
            az0  = fmaf(iv, Wz[k], az0);    az1  = fmaf(iv, Wz[xK + k], az1);
            ain0 = fmaf(iv, Wn[k], ain0);   ain1 = fmaf(iv, Wn[xK + k], ain1);
        }
    }

    const float* hbase = hin + (size_t)b0 * H_;
    for (int kc = 0; kc < H_; kc += 32) {
        stage_tile(tiles + par * 512, hbase, (size_t)H_, kc, tid);
        __syncthreads();
        read_inregs(tiles + par * 512, lane, in_r);
        par ^= 1;
        const float* Wr = Whh + (size_t)jA * H_ + kc;
        const float* Wz = Wr + (size_t)H_ * H_;
        const float* Wn = Wz + (size_t)H_ * H_;
#pragma unroll
        for (int k = 0; k < 32; ++k) {
            float iv = in_r[k];
            ar0  = fmaf(iv, Wr[k], ar0);    ar1  = fmaf(iv, Wr[H_ + k], ar1);
            az0  = fmaf(iv, Wz[k], az0);    az1  = fmaf(iv, Wz[H_ + k], az1);
            ahn0 = fmaf(iv, Wn[k], ahn0);   ahn1 = fmaf(iv, Wn[H_ + k], ahn1);
        }
    }

    // epilogue: gate math
    float2 hold = *(const float2*)(hin + (size_t)b * H_ + jA);
    float br0 = bih[jA]        + bhh[jA];
    float br1 = bih[jA + 1]    + bhh[jA + 1];
    float bz0 = bih[H_ + jA]   + bhh[H_ + jA];
    float bz1 = bih[H_ + jA+1] + bhh[H_ + jA + 1];
    float bi0 = bih[2*H_ + jA],     bi1 = bih[2*H_ + jA + 1];
    float bh0 = bhh[2*H_ + jA],     bh1 = bhh[2*H_ + jA + 1];
    float r0 = 1.f / (1.f + expf(-(ar0 + br0)));
    float r1 = 1.f / (1.f + expf(-(ar1 + br1)));
    float z0 = 1.f / (1.f + expf(-(az0 + bz0)));
    float z1 = 1.f / (1.f + expf(-(az1 + bz1)));
    float n0 = tanhf(ain0 + bi0 + r0 * (ahn0 + bh0));
    float n1 = tanhf(ain1 + bi1 + r1 * (ahn1 + bh1));
    float h0v = (1.f - z0) * n0 + z0 * hold.x;
    float h1v = (1.f - z1) * n1 + z1 * hold.y;
    *(float2*)(hout + (size_t)b * H_ + jA) = make_float2(h0v, h1v);
    if (encout)
        *(float2*)(encout + (size_t)b * enc_pitch + jA) = make_float2(h0v, h1v);
}

// hw2[b][a] = sum_k h[b][k] * w2[a][k]. Same structure as gru_phase.
__device__ __forceinline__ void w2_phase(
    int tid, int bid,
    const float* __restrict__ h, const float* __restrict__ w2,
    float* __restrict__ hw2, float4* __restrict__ tiles)
{
    const int lane = tid & 63;
    const int wvu  = __builtin_amdgcn_readfirstlane(tid >> 6);
    const int b0   = (bid >> 6) * 64;
    const int aA   = (bid & 63) * 8 + wvu * 2;
    float a0 = 0.f, a1 = 0.f;
    float in_r[32];
    int par = 0;
    const float* hbase = h + (size_t)b0 * H_;
    for (int kc = 0; kc < H_; kc += 32) {
        stage_tile(tiles + par * 512, hbase, (size_t)H_, kc, tid);
        __syncthreads();
        read_inregs(tiles + par * 512, lane, in_r);
        par ^= 1;
        const float* Wa = w2 + (size_t)aA * H_ + kc;
#pragma unroll
        for (int k = 0; k < 32; ++k) {
            a0 = fmaf(in_r[k], Wa[k], a0);
            a1 = fmaf(in_r[k], Wa[H_ + k], a1);
        }
    }
    *(float2*)(hw2 + (size_t)(b0 + lane) * A_ + aA) = make_float2(a0, a1);
}

// ---------------------------------------------------------------------------
// Persistent encoder: init + 128 GRU steps with grid sync.
// ---------------------------------------------------------------------------
__global__ __launch_bounds__(256) void enc_kernel(
    const float* __restrict__ x,
    const float* __restrict__ Wih, const float* __restrict__ Whh,
    const float* __restrict__ bih, const float* __restrict__ bhh,
    float* __restrict__ h0b, float* __restrict__ h1b,
    float* __restrict__ enc_out, float* __restrict__ dec_in)
{
    cg::grid_group gg = cg::this_grid();
    __shared__ float4 tiles[1024];
    const int tid = threadIdx.x, bid = blockIdx.x;
    const size_t gid = (size_t)bid * 256 + tid;

    h0b[gid] = 0.f;
    h0b[gid + 65536] = 0.f;
    if (gid < 32768) dec_in[gid] = 0.f;
    gg.sync();

    float* hA = h0b;
    float* hB = h1b;
    for (int t = 0; t < S_; ++t) {
        gru_phase(tid, bid, x + (size_t)t * F_, (size_t)(S_ * F_), F_,
                  hA, Wih, Whh, bih, bhh, hB,
                  enc_out + (size_t)t * H_, (size_t)(S_ * H_), tiles);
        gg.sync();
        float* tmp = hA; hA = hB; hB = tmp;
    }
}

// ---------------------------------------------------------------------------
// Persistent decoder: 128 x (GRU -> h@w2^T -> attention/softmax/argmax/gather)
// ---------------------------------------------------------------------------
__global__ __launch_bounds__(256) void dec_kernel(
    const float* __restrict__ x, const int* __restrict__ y,
    const float* __restrict__ Wih, const float* __restrict__ Whh,
    const float* __restrict__ bih, const float* __restrict__ bhh,
    const float* __restrict__ w2, const float* __restrict__ v,
    const float* __restrict__ ep,
    float* __restrict__ h0b, float* __restrict__ h1b,
    float* __restrict__ hw2, float* __restrict__ dec_in,
    float* __restrict__ nlogp, float* __restrict__ preds)
{
    cg::grid_group gg = cg::this_grid();
    __shared__ float4 tiles[1024];
    __shared__ float sScore[S_], sProb[S_];
    __shared__ int sPred;
    const int tid = threadIdx.x, bid = blockIdx.x;
    const int ln = tid & 63, wv = tid >> 6;

    // v fragment per lane, persists across all steps
    float4 v0r = *(const float4*)(v + ln * 8);
    float4 v1r = *(const float4*)(v + ln * 8 + 4);

    float* hA = h0b;
    float* hB = h1b;
    for (int i = 0; i < C_; ++i) {
        gru_phase(tid, bid, dec_in, (size_t)F_, F_,
                  hA, Wih, Whh, bih, bhh, hB, (float*)nullptr, 0, tiles);
        gg.sync();
        w2_phase(tid, bid, hB, w2, hw2, tiles);
        gg.sync();

        // ---- attention: block bid handles batch element b = bid ----
        {
            const int b = bid;
            float4 q0 = *(const float4*)(hw2 + (size_t)b * A_ + ln * 8);
            float4 q1 = *(const float4*)(hw2 + (size_t)b * A_ + ln * 8 + 4);
            const float* epb = ep + (size_t)b * (S_ * A_);
            for (int si = 0; si < S_ / 4; ++si) {
                int s = si * 4 + wv;
                const float* row = epb + (size_t)s * A_ + ln * 8;
                float4 p0 = *(const float4*)(row);
                float4 p1 = *(const float4*)(row + 4);
                float acc = fmaxf(p0.x + q0.x, 0.f) * v0r.x
                          + fmaxf(p0.y + q0.y, 0.f) * v0r.y
                          + fmaxf(p0.z + q0.z, 0.f) * v0r.z
                          + fmaxf(p0.w + q0.w, 0.f) * v0r.w
                          + fmaxf(p1.x + q1.x, 0.f) * v1r.x
                          + fmaxf(p1.y + q1.y, 0.f) * v1r.y
                          + fmaxf(p1.z + q1.z, 0.f) * v1r.z
                          + fmaxf(p1.w + q1.w, 0.f) * v1r.w;
#pragma unroll
                for (int off = 32; off; off >>= 1) acc += __shfl_down(acc, off);
                if (ln == 0) sScore[s] = acc;
            }
            __syncthreads();

            if (tid < 64) {
                float s0v = sScore[tid], s1v = sScore[tid + 64];
                float m = fmaxf(s0v, s1v);
#pragma unroll
                for (int off = 32; off; off >>= 1) m = fmaxf(m, __shfl_xor(m, off));
                float e0 = expf(s0v - m), e1 = expf(s1v - m);
                float se = e0 + e1;
#pragma unroll
                for (int off = 32; off; off >>= 1) se += __shfl_xor(se, off);
                float p0 = e0 / se, p1 = e1 / se;
                sProb[tid] = p0; sProb[tid + 64] = p1;
                float pm = fmaxf(p0, p1);
#pragma unroll
                for (int off = 32; off; off >>= 1) pm = fmaxf(pm, __shfl_xor(pm, off));
                float t0 = expf(p0 - pm), t1 = expf(p1 - pm);
                float T = t0 + t1;
#pragma unroll
                for (int off = 32; off; off >>= 1) T += __shfl_xor(T, off);
                float bv = p0; int bi2 = tid;
                if (p1 > bv) { bv = p1; bi2 = tid + 64; }
#pragma unroll
                for (int off = 32; off; off >>= 1) {
                    float ov = __shfl_xor(bv, off);
                    int oi = __shfl_xor(bi2, off);
                    if (ov > bv || (ov == bv && oi < bi2)) { bv = ov; bi2 = oi; }
                }
                if (tid == 0) {
                    sPred = bi2;
                    int yy = y[(size_t)b * C_ + i];
                    float py = sProb[yy];
                    nlogp[(size_t)i * B_ + b] = -(py - pm - logf(T));
                    preds[(size_t)b * C_ + i] = (float)bi2;
                }
            }
            __syncthreads();

            const int pred = sPred;
            if (tid < 32) {
                const float4* src = (const float4*)(x + ((size_t)b * S_ + pred) * F_);
                float4* dst = (float4*)(dec_in + (size_t)b * F_);
                dst[tid] = src[tid];
            }
        }
        gg.sync();
        float* tmp = hA; hA = hB; hB = tmp;
    }
}

// ---------------------------------------------------------------------------
// enc_proj = enc_out @ w1^T  (big parallel GEMM, normal launch)
// ---------------------------------------------------------------------------
template<int BM, int BN, int TM, int TN>
__global__ __launch_bounds__(256)
void gemm_nt(const float* __restrict__ A, const float* __restrict__ Bw,
             float* __restrict__ C, int M, int N, int K)
{
    constexpr int KC = 32;
    constexpr int TX = BN / TN;
    constexpr int TY = BM / TM;
    __shared__ float4 sA[(KC / 4) * BM];
    __shared__ float4 sB[(KC / 4) * BN];

    const int tid = threadIdx.x;
    const int tx = tid % TX, ty = tid / TX;
    const int m0 = blockIdx.y * BM, n0 = blockIdx.x * BN;

    float acc[TM][TN];
#pragma unroll
    for (int i = 0; i < TM; i++)
#pragma unroll
        for (int jj = 0; jj < TN; jj++) acc[i][jj] = 0.f;

    for (int kc = 0; kc < K; kc += KC) {
        for (int idx = tid; idx < BM * 8; idx += 256) {
            int r = idx >> 3, kv = idx & 7;
            sA[kv * BM + r] = *(const float4*)(A + (size_t)(m0 + r) * K + kc + kv * 4);
        }
        for (int idx = tid; idx < BN * 8; idx += 256) {
            int r = idx >> 3, kv = idx & 7;
            sB[kv * BN + r] = *(const float4*)(Bw + (size_t)(n0 + r) * K + kc + kv * 4);
        }
        __syncthreads();
#pragma unroll
        for (int kk = 0; kk < KC / 4; ++kk) {
            float4 af[TM], bf[TN];
#pragma unroll
            for (int i = 0; i < TM; i++) af[i] = sA[kk * BM + ty + i * TY];
#pragma unroll
            for (int jj = 0; jj < TN; jj++) bf[jj] = sB[kk * BN + tx + jj * TX];
#pragma unroll
            for (int i = 0; i < TM; i++)
#pragma unroll
                for (int jj = 0; jj < TN; jj++)
                    acc[i][jj] += DOT4(af[i], bf[jj]);
        }
        __syncthreads();
    }
#pragma unroll
    for (int i = 0; i < TM; i++)
#pragma unroll
        for (int jj = 0; jj < TN; jj++)
            C[(size_t)(m0 + ty + i * TY) * N + n0 + tx + jj * TX] = acc[i][jj];
}

__global__ void final_loss(const float* __restrict__ nlogp, float* __restrict__ out)
{
    __shared__ float part[C_];
    const int i = threadIdx.x; // 128
    float s = 0.f;
    for (int b = 0; b < B_; ++b) s += nlogp[(size_t)i * B_ + b];
    part[i] = s / (float)B_;
    __syncthreads();
    if (i == 0) {
        float t = 0.f;
        for (int k = 0; k < C_; ++k) t += part[k];
        out[0] = t / (float)B_ / (float)C_;
    }
}

extern "C" void kernel_launch(void* const* d_in, const int* in_sizes, int n_in,
                              void* d_out, int out_size, void* d_ws, size_t ws_size,
                              hipStream_t stream)
{
    (void)in_sizes; (void)n_in; (void)out_size; (void)ws_size;
    const float* x    = (const float*)d_in[0];
    const int*   y    = (const int*)d_in[1];
    const float* eWih = (const float*)d_in[2];
    const float* eWhh = (const float*)d_in[3];
    const float* ebih = (const float*)d_in[4];
    const float* ebhh = (const float*)d_in[5];
    const float* dWih = (const float*)d_in[6];
    const float* dWhh = (const float*)d_in[7];
    const float* dbih = (const float*)d_in[8];
    const float* dbhh = (const float*)d_in[9];
    const float* w1   = (const float*)d_in[10];
    const float* w2   = (const float*)d_in[11];
    const float* v    = (const float*)d_in[12];
    float* out = (float*)d_out;

    float* ws = (float*)d_ws;
    float* enc_out  = ws;                       // B*S*H = 16777216
    float* enc_proj = enc_out + 16777216;       // B*S*A = 16777216
    float* hbuf0    = enc_proj + 16777216;      // B*H = 131072
    float* hbuf1    = hbuf0 + 131072;
    float* hw2buf   = hbuf1 + 131072;           // B*A = 131072
    float* dec_in   = hw2buf + 131072;          // B*F = 32768
    float* nlogp    = dec_in + 32768;           // C*B = 32768

    {
        void* a[] = { (void*)&x, (void*)&eWih, (void*)&eWhh, (void*)&ebih,
                      (void*)&ebhh, (void*)&hbuf0, (void*)&hbuf1,
                      (void*)&enc_out, (void*)&dec_in };
        hipLaunchCooperativeKernel((const void*)enc_kernel,
                                   dim3(256), dim3(256), a, 0, stream);
    }

    gemm_nt<64, 64, 4, 4><<<dim3(A_ / 64, (B_ * S_) / 64), 256, 0, stream>>>(
        enc_out, w1, enc_proj, B_ * S_, A_, H_);

    {
        void* a[] = { (void*)&x, (void*)&y, (void*)&dWih, (void*)&dWhh,
                      (void*)&dbih, (void*)&dbhh, (void*)&w2, (void*)&v,
                      (void*)&enc_proj, (void*)&hbuf0, (void*)&hbuf1,
                      (void*)&hw2buf, (void*)&dec_in, (void*)&nlogp,
                      (void*)&out };
        hipLaunchCooperativeKernel((const void*)dec_kernel,
                                   dim3(256), dim3(256), a, 0, stream);
    }

    final_loss<<<dim3(1), 128, 0, stream>>>(nlogp, out + (size_t)B_ * C_);
}